// Round 15
// baseline (273.840 us; speedup 1.0000x reference)
//
#include <hip/hip_runtime.h>

#define N_NODES 100000
#define N_EDGES 1600000
#define IN_CH   128
#define HID     64
#define NG      256
#define NFILL   4    // dst-range passes for L2-resident scatter
#define CAP     64   // padded CSR slots per node (max deg ~42 for Poisson(16))

typedef __attribute__((ext_vector_type(8))) short bf16x8;
typedef __attribute__((ext_vector_type(4))) float f32x4;

// ---- round-to-nearest-even f32 -> bf16 bits ----
__device__ __forceinline__ unsigned short f2bf(float f) {
    union { float f; unsigned u; } v; v.f = f;
    unsigned r = v.u + 0x7FFF + ((v.u >> 16) & 1);
    return (unsigned short)(r >> 16);
}
__device__ __forceinline__ float bfval(unsigned short h) {
    return __uint_as_float((unsigned)h << 16);
}
__device__ __forceinline__ float bf_lo(unsigned int p) { return __uint_as_float(p << 16); }
__device__ __forceinline__ float bf_hi(unsigned int p) { return __uint_as_float(p & 0xFFFF0000u); }

// ---- zero fillpos (replaces pathologically slow rocclr fillBuffer) ----
__global__ void k_zero(int* __restrict__ p, int n4) {
    int i = blockIdx.x * blockDim.x + threadIdx.x;
    if (i < n4) reinterpret_cast<int4*>(p)[i] = (int4){0, 0, 0, 0};
}

// ---- padded CSR fill (range pass): count + place in one atomic ----
__global__ void k_fill(const int* __restrict__ src, const int* __restrict__ dst,
                       int* __restrict__ fillpos, int* __restrict__ col,
                       int lo, int hi) {
    int e = blockIdx.x * blockDim.x + threadIdx.x;
    if (e >= N_EDGES) return;
    int d = dst[e];
    if (d < lo || d >= hi) return;
    int p = atomicAdd(&fillpos[d], 1);
    if (p < CAP) col[(long)d * CAP + p] = src[e];
}

// ---- pad row tail [deg, round16(deg)) with self index (for check-free gather) ----
__global__ void k_pad(const int* __restrict__ deg, int* __restrict__ col) {
    int i = blockIdx.x * blockDim.x + threadIdx.x;
    if (i >= N_NODES) return;
    int n = deg[i];
    n = n < CAP ? n : CAP;
    int n16 = (n + 15) & ~15;
    int* crow = col + (long)i * CAP;
    for (int p = n; p < n16; ++p) crow[p] = i;
}

// ---- dinv[i] = rsqrt(deg[i] + 1); deg == fillpos after fills ----
__global__ void k_dinv(const int* __restrict__ deg, float* __restrict__ dinv) {
    int i = blockIdx.x * blockDim.x + threadIdx.x;
    if (i < N_NODES) dinv[i] = rsqrtf((float)deg[i] + 1.0f);
}

// ---- W transpose + hi/lo bf16 split: Wt[c][k] = bf16split(W[k][c]) ----
__global__ void k_wcvt(const float* __restrict__ W, unsigned short* __restrict__ Whi,
                       unsigned short* __restrict__ Wlo, int K) {
    int t = blockIdx.x * blockDim.x + threadIdx.x;
    if (t >= 64 * K) return;
    int c = t / K, k = t - c * K;
    float v = W[k * 64 + c];
    unsigned short h = f2bf(v);
    Whi[t] = h;
    Wlo[t] = f2bf(v - bfval(h));
}

// ---- linear v8: MFMA GEMM. Wave = 16 rows x 64 cols, K in 32-chunks.
// A = x rows, split hi/lo bf16 in-kernel; B = pre-split Wt (hi/lo).
// 3 MFMAs per (kk,cb): hh + lh + hl.
// hs[i][j] = bf16( dinv[i] * sum_k x[i][k]*W[k][j] )
template <int K>
__global__ void __launch_bounds__(256) k_linear(const float* __restrict__ x,
                                                const unsigned short* __restrict__ Whi,
                                                const unsigned short* __restrict__ Wlo,
                                                const float* __restrict__ dinv,
                                                unsigned short* __restrict__ hs) {
    const int wid = (blockIdx.x * blockDim.x + threadIdx.x) >> 6;
    const int lane = threadIdx.x & 63;
    const int row16 = lane & 15;     // A-row / B-col within tile
    const int kg = lane >> 4;        // k-group 0..3
    const int r0 = wid * 16;
    if (r0 >= N_NODES) return;

    f32x4 acc[4];
#pragma unroll
    for (int cb = 0; cb < 4; ++cb) acc[cb] = (f32x4){0.f, 0.f, 0.f, 0.f};

    const float* xrow = x + (long)(r0 + row16) * K;

#pragma unroll
    for (int kk = 0; kk < K / 32; ++kk) {
        const float* ap = xrow + kk * 32 + kg * 8;
        float4 af0 = *reinterpret_cast<const float4*>(ap);
        float4 af1 = *reinterpret_cast<const float4*>(ap + 4);
        bf16x8 ahi, alo;
#define CVT(i, val) { unsigned short h_ = f2bf(val); ahi[i] = (short)h_; \
                      alo[i] = (short)f2bf((val) - bfval(h_)); }
        CVT(0, af0.x) CVT(1, af0.y) CVT(2, af0.z) CVT(3, af0.w)
        CVT(4, af1.x) CVT(5, af1.y) CVT(6, af1.z) CVT(7, af1.w)
#undef CVT
#pragma unroll
        for (int cb = 0; cb < 4; ++cb) {
            long boff = (long)(cb * 16 + row16) * K + kk * 32 + kg * 8;
            bf16x8 bh = *reinterpret_cast<const bf16x8*>(Whi + boff);
            bf16x8 bl = *reinterpret_cast<const bf16x8*>(Wlo + boff);
            acc[cb] = __builtin_amdgcn_mfma_f32_16x16x32_bf16(ahi, bh, acc[cb], 0, 0, 0);
            acc[cb] = __builtin_amdgcn_mfma_f32_16x16x32_bf16(alo, bh, acc[cb], 0, 0, 0);
            acc[cb] = __builtin_amdgcn_mfma_f32_16x16x32_bf16(ahi, bl, acc[cb], 0, 0, 0);
        }
    }

    // epilogue: C layout col=lane&15, row=(lane>>4)*4+reg (m89-verified)
#pragma unroll
    for (int reg = 0; reg < 4; ++reg) {
        int n = r0 + kg * 4 + reg;
        float d = dinv[n];
#pragma unroll
        for (int cb = 0; cb < 4; ++cb)
            hs[(long)n * 64 + cb * 16 + row16] = f2bf(acc[cb][reg] * d);
    }
}

// ---- gather v4: predication-free. Rows padded to mult-of-16 with self index;
// surplus self contributions subtracted once at the end.
// out[i][j] = relu( dinv[i] * ( sum_e hs[col[e]][j] + hs[i][j] ) + b[j] )
__global__ void k_gather(const int* __restrict__ deg, const int* __restrict__ col,
                         const unsigned int* __restrict__ hs2,   // packed bf16x2, 32/row
                         const float* __restrict__ dinv, const float* __restrict__ bias,
                         float* __restrict__ out) {
    int t = blockIdx.x * blockDim.x + threadIdx.x;
    int lane = t & 63;
    int half = lane >> 5;           // which node of the wave's pair
    int c2 = lane & 31;             // channel-pair index (channels 2c2, 2c2+1)
    int i = ((t >> 6) << 1) + half; // node
    if (i >= N_NODES) return;
    const int4* crow4 = reinterpret_cast<const int4*>(col + (long)i * CAP);
    int n = deg[i];
    n = n < CAP ? n : CAP;
    int n16 = (n + 15) & ~15;
    const unsigned int* hsc = hs2 + c2;
    unsigned int self = hsc[(long)i * 32];
    float selfL = bf_lo(self), selfH = bf_hi(self);
    float aL = selfL, aH = selfH;

    for (int e0 = 0; e0 < n16; e0 += 16) {
        int4 q0 = crow4[(e0 >> 2) + 0];
        int4 q1 = crow4[(e0 >> 2) + 1];
        int4 q2 = crow4[(e0 >> 2) + 2];
        int4 q3 = crow4[(e0 >> 2) + 3];
        unsigned int v[16];
        v[0]  = hsc[(long)q0.x * 32]; v[1]  = hsc[(long)q0.y * 32];
        v[2]  = hsc[(long)q0.z * 32]; v[3]  = hsc[(long)q0.w * 32];
        v[4]  = hsc[(long)q1.x * 32]; v[5]  = hsc[(long)q1.y * 32];
        v[6]  = hsc[(long)q1.z * 32]; v[7]  = hsc[(long)q1.w * 32];
        v[8]  = hsc[(long)q2.x * 32]; v[9]  = hsc[(long)q2.y * 32];
        v[10] = hsc[(long)q2.z * 32]; v[11] = hsc[(long)q2.w * 32];
        v[12] = hsc[(long)q3.x * 32]; v[13] = hsc[(long)q3.y * 32];
        v[14] = hsc[(long)q3.z * 32]; v[15] = hsc[(long)q3.w * 32];
#pragma unroll
        for (int j = 0; j < 16; ++j) {
            aL += bf_lo(v[j]);
            aH += bf_hi(v[j]);
        }
    }
    // remove surplus self contributions from the pad slots
    float fE = (float)(n16 - n);
    aL = fmaf(-fE, selfL, aL);
    aH = fmaf(-fE, selfH, aH);

    float di = dinv[i];
    float vL = fmaf(di, aL, bias[2 * c2]);
    float vH = fmaf(di, aH, bias[2 * c2 + 1]);
    float2 o;
    o.x = vL > 0.f ? vL : 0.f;
    o.y = vH > 0.f ? vH : 0.f;
    *reinterpret_cast<float2*>(&out[(long)i * 64 + 2 * c2]) = o;
}

// ---- graph boundaries from sorted batch ----
__global__ void k_bounds(const int* __restrict__ batch, int* __restrict__ start) {
    int i = blockIdx.x * blockDim.x + threadIdx.x;
    if (i >= N_NODES) return;
    int b = batch[i];
    int prev = (i == 0) ? -1 : batch[i - 1];
    for (int g = prev + 1; g <= b; ++g) start[g] = i;
    if (i == N_NODES - 1)
        for (int g = b + 1; g <= NG; ++g) start[g] = N_NODES;
}

// ---- fused mean-pool + head MLP: one 256-thread block per graph ----
__global__ void k_poolhead(const float* __restrict__ a, const int* __restrict__ start,
                           const float* __restrict__ Wc1, const float* __restrict__ bc1,
                           const float* __restrict__ Wc2, const float* __restrict__ bc2,
                           float* __restrict__ out) {
    __shared__ float partial[4][64];
    __shared__ float gvec[64];
    __shared__ float tvec[32];
    int g = blockIdx.x;
    int w = threadIdx.x >> 6;
    int j = threadIdx.x & 63;
    int s0 = start[g], s1 = start[g + 1];
    float acc = 0.f;
    for (int i = s0 + w; i < s1; i += 4)
        acc += a[(long)i * 64 + j];
    partial[w][j] = acc;
    __syncthreads();
    if (w == 0) {
        float c = (float)(s1 - s0);
        c = c > 1.f ? c : 1.f;
        gvec[j] = (partial[0][j] + partial[1][j] + partial[2][j] + partial[3][j]) / c;
    }
    __syncthreads();
    if (threadIdx.x < 32) {
        int jj = threadIdx.x;
        float acc2 = bc1[jj];
#pragma unroll 8
        for (int k = 0; k < 64; ++k) acc2 = fmaf(gvec[k], Wc1[k * 32 + jj], acc2);
        tvec[jj] = acc2 > 0.f ? acc2 : 0.f;
    }
    __syncthreads();
    if (threadIdx.x < 2) {
        int jj = threadIdx.x;
        float acc2 = bc2[jj];
#pragma unroll
        for (int k = 0; k < 32; ++k) acc2 = fmaf(tvec[k], Wc2[k * 2 + jj], acc2);
        out[g * 2 + jj] = acc2;
    }
}

extern "C" void kernel_launch(void* const* d_in, const int* in_sizes, int n_in,
                              void* d_out, int out_size, void* d_ws, size_t ws_size,
                              hipStream_t stream) {
    const float* x    = (const float*)d_in[0];
    const int*   ei   = (const int*)d_in[1];
    const int*   batch= (const int*)d_in[2];
    const float* W1   = (const float*)d_in[3];
    const float* b1   = (const float*)d_in[4];
    const float* W2   = (const float*)d_in[5];
    const float* b2   = (const float*)d_in[6];
    const float* Wc1  = (const float*)d_in[7];
    const float* bc1  = (const float*)d_in[8];
    const float* Wc2  = (const float*)d_in[9];
    const float* bc2  = (const float*)d_in[10];
    float* out = (float*)d_out;

    const int* src = ei;            // edge_index[0]
    const int* dst = ei + N_EDGES;  // edge_index[1]

    char* ws = (char*)d_ws;
    size_t off = 0;
    auto alloc = [&](size_t bytes) {
        void* p = ws + off;
        off += (bytes + 255) & ~(size_t)255;
        return p;
    };
    unsigned short* hs = (unsigned short*)alloc((size_t)N_NODES * HID * 2);   // 12.8MB bf16
    float* agg     = (float*)alloc((size_t)N_NODES * HID * sizeof(float));    // 25.6MB
    int*   col     = (int*)  alloc((size_t)N_NODES * CAP * sizeof(int) + 256);// 25.6MB padded CSR
    float* dinv    = (float*)alloc(N_NODES * sizeof(float));
    int*   fillpos = (int*)  alloc((N_NODES + 4) * sizeof(int));  // becomes deg
    int*   start   = (int*)  alloc((NG + 1) * sizeof(int));
    unsigned short* W1hi = (unsigned short*)alloc(64 * IN_CH * 2);  // transposed bf16
    unsigned short* W1lo = (unsigned short*)alloc(64 * IN_CH * 2);
    unsigned short* W2hi = (unsigned short*)alloc(64 * HID * 2);
    unsigned short* W2lo = (unsigned short*)alloc(64 * HID * 2);

    const int TB = 256;

    // weight transpose + hi/lo split (tiny)
    k_wcvt<<<(64 * IN_CH + TB - 1) / TB, TB, 0, stream>>>(W1, W1hi, W1lo, IN_CH);
    k_wcvt<<<(64 * HID + TB - 1) / TB, TB, 0, stream>>>(W2, W2hi, W2lo, HID);

    // padded CSR build: zero counts, fill passes, pad tails
    {
        const int nz4 = (N_NODES + 3) / 4;
        k_zero<<<(nz4 + TB - 1) / TB, TB, 0, stream>>>(fillpos, nz4);
        const int step = (N_NODES + NFILL - 1) / NFILL;
        for (int p = 0; p < NFILL; ++p) {
            int lo = p * step;
            int hi = lo + step < N_NODES ? lo + step : N_NODES;
            k_fill<<<(N_EDGES + TB - 1) / TB, TB, 0, stream>>>(src, dst, fillpos, col, lo, hi);
        }
        k_pad<<<(N_NODES + TB - 1) / TB, TB, 0, stream>>>(fillpos, col);
    }
    k_dinv<<<(N_NODES + TB - 1) / TB, TB, 0, stream>>>(fillpos, dinv);

    // graph boundaries
    k_bounds<<<(N_NODES + TB - 1) / TB, TB, 0, stream>>>(batch, start);

    const int gatherBlocks = ((N_NODES + 1) / 2 * 64 + TB - 1) / TB;
    const int linBlocks = ((N_NODES + 15) / 16 + 3) / 4;   // 4 waves/block, 16 rows/wave

    // layer 1
    k_linear<IN_CH><<<linBlocks, 256, 0, stream>>>(x, W1hi, W1lo, dinv, hs);
    k_gather<<<gatherBlocks, TB, 0, stream>>>(fillpos, col, (const unsigned int*)hs, dinv, b1, agg);

    // layer 2
    k_linear<HID><<<linBlocks, 256, 0, stream>>>(agg, W2hi, W2lo, dinv, hs);
    k_gather<<<gatherBlocks, TB, 0, stream>>>(fillpos, col, (const unsigned int*)hs, dinv, b2, agg);

    // fused mean-pool + head
    k_poolhead<<<NG, 256, 0, stream>>>(agg, start, Wc1, bc1, Wc2, bc2, out);
}

// Round 16
// 273.129 us; speedup vs baseline: 1.0026x; 1.0026x over previous
//
#include <hip/hip_runtime.h>

#define N_NODES 100000
#define N_EDGES 1600000
#define IN_CH   128
#define HID     64
#define NG      256
#define NFILL   4    // dst-range passes for L2-resident scatter
#define CAP     64   // padded CSR slots per node (max deg ~42 for Poisson(16))

typedef __attribute__((ext_vector_type(8))) short bf16x8;
typedef __attribute__((ext_vector_type(4))) float f32x4;

// ---- round-to-nearest-even f32 -> bf16 bits ----
__device__ __forceinline__ unsigned short f2bf(float f) {
    union { float f; unsigned u; } v; v.f = f;
    unsigned r = v.u + 0x7FFF + ((v.u >> 16) & 1);
    return (unsigned short)(r >> 16);
}
__device__ __forceinline__ float bfval(unsigned short h) {
    return __uint_as_float((unsigned)h << 16);
}
__device__ __forceinline__ float bf_lo(unsigned int p) { return __uint_as_float(p << 16); }
__device__ __forceinline__ float bf_hi(unsigned int p) { return __uint_as_float(p & 0xFFFF0000u); }

// ---- zero fillpos ----
__global__ void k_zero(int* __restrict__ p, int n4) {
    int i = blockIdx.x * blockDim.x + threadIdx.x;
    if (i < n4) reinterpret_cast<int4*>(p)[i] = (int4){0, 0, 0, 0};
}

// ---- padded CSR fill (range pass): count + place in one atomic ----
__global__ void k_fill(const int* __restrict__ src, const int* __restrict__ dst,
                       int* __restrict__ fillpos, int* __restrict__ col,
                       int lo, int hi) {
    int e = blockIdx.x * blockDim.x + threadIdx.x;
    if (e >= N_EDGES) return;
    int d = dst[e];
    if (d < lo || d >= hi) return;
    int p = atomicAdd(&fillpos[d], 1);
    if (p < CAP) col[(long)d * CAP + p] = src[e];
}

// ---- fused: dinv + pad row tail with self index ----
__global__ void k_dinvpad(const int* __restrict__ deg, float* __restrict__ dinv,
                          int* __restrict__ col) {
    int i = blockIdx.x * blockDim.x + threadIdx.x;
    if (i >= N_NODES) return;
    int n = deg[i];
    dinv[i] = rsqrtf((float)n + 1.0f);
    n = n < CAP ? n : CAP;
    int n16 = (n + 15) & ~15;
    int* crow = col + (long)i * CAP;
    for (int p = n; p < n16; ++p) crow[p] = i;
}

// ---- W transpose + hi/lo bf16 split: Wt[c][k] = bf16split(W[k][c]) ----
__global__ void k_wcvt(const float* __restrict__ W, unsigned short* __restrict__ Whi,
                       unsigned short* __restrict__ Wlo, int K) {
    int t = blockIdx.x * blockDim.x + threadIdx.x;
    if (t >= 64 * K) return;
    int c = t / K, k = t - c * K;
    float v = W[k * 64 + c];
    unsigned short h = f2bf(v);
    Whi[t] = h;
    Wlo[t] = f2bf(v - bfval(h));
}

// ---- linear v9: MFMA GEMM with FULL x-row register prefetch (one latency
// exposure per wave). Wave = 16 rows x 64 cols; A split hi/lo bf16 in-kernel;
// B pre-split Wt (L1-hot). hs[i][j] = bf16( dinv[i] * sum_k x[i][k]*W[k][j] )
template <int K>
__global__ void __launch_bounds__(256) k_linear(const float* __restrict__ x,
                                                const unsigned short* __restrict__ Whi,
                                                const unsigned short* __restrict__ Wlo,
                                                const float* __restrict__ dinv,
                                                unsigned short* __restrict__ hs) {
    const int wid = (blockIdx.x * blockDim.x + threadIdx.x) >> 6;
    const int lane = threadIdx.x & 63;
    const int row16 = lane & 15;     // A-row / B-col within tile
    const int kg = lane >> 4;        // k-group 0..3
    const int r0 = wid * 16;
    if (r0 >= N_NODES) return;

    f32x4 acc[4];
#pragma unroll
    for (int cb = 0; cb < 4; ++cb) acc[cb] = (f32x4){0.f, 0.f, 0.f, 0.f};

    const float* xrow = x + (long)(r0 + row16) * K;

    // prefetch ALL x chunks back-to-back: K/32*2 independent loads in flight
    float4 xf0[K / 32], xf1[K / 32];
#pragma unroll
    for (int kk = 0; kk < K / 32; ++kk) {
        const float* ap = xrow + kk * 32 + kg * 8;
        xf0[kk] = *reinterpret_cast<const float4*>(ap);
        xf1[kk] = *reinterpret_cast<const float4*>(ap + 4);
    }

#pragma unroll
    for (int kk = 0; kk < K / 32; ++kk) {
        bf16x8 ahi, alo;
#define CVT(i, val) { unsigned short h_ = f2bf(val); ahi[i] = (short)h_; \
                      alo[i] = (short)f2bf((val) - bfval(h_)); }
        CVT(0, xf0[kk].x) CVT(1, xf0[kk].y) CVT(2, xf0[kk].z) CVT(3, xf0[kk].w)
        CVT(4, xf1[kk].x) CVT(5, xf1[kk].y) CVT(6, xf1[kk].z) CVT(7, xf1[kk].w)
#undef CVT
#pragma unroll
        for (int cb = 0; cb < 4; ++cb) {
            long boff = (long)(cb * 16 + row16) * K + kk * 32 + kg * 8;
            bf16x8 bh = *reinterpret_cast<const bf16x8*>(Whi + boff);
            bf16x8 bl = *reinterpret_cast<const bf16x8*>(Wlo + boff);
            acc[cb] = __builtin_amdgcn_mfma_f32_16x16x32_bf16(ahi, bh, acc[cb], 0, 0, 0);
            acc[cb] = __builtin_amdgcn_mfma_f32_16x16x32_bf16(alo, bh, acc[cb], 0, 0, 0);
            acc[cb] = __builtin_amdgcn_mfma_f32_16x16x32_bf16(ahi, bl, acc[cb], 0, 0, 0);
        }
    }

    // epilogue: C layout col=lane&15, row=(lane>>4)*4+reg (m89-verified)
#pragma unroll
    for (int reg = 0; reg < 4; ++reg) {
        int n = r0 + kg * 4 + reg;
        float d = dinv[n];
#pragma unroll
        for (int cb = 0; cb < 4; ++cb)
            hs[(long)n * 64 + cb * 16 + row16] = f2bf(acc[cb][reg] * d);
    }
}

// ---- gather v4: predication-free. Rows padded to mult-of-16 with self index;
// surplus self contributions subtracted once at the end.
// out[i][j] = relu( dinv[i] * ( sum_e hs[col[e]][j] + hs[i][j] ) + b[j] )
__global__ void k_gather(const int* __restrict__ deg, const int* __restrict__ col,
                         const unsigned int* __restrict__ hs2,   // packed bf16x2, 32/row
                         const float* __restrict__ dinv, const float* __restrict__ bias,
                         float* __restrict__ out) {
    int t = blockIdx.x * blockDim.x + threadIdx.x;
    int lane = t & 63;
    int half = lane >> 5;           // which node of the wave's pair
    int c2 = lane & 31;             // channel-pair index (channels 2c2, 2c2+1)
    int i = ((t >> 6) << 1) + half; // node
    if (i >= N_NODES) return;
    const int4* crow4 = reinterpret_cast<const int4*>(col + (long)i * CAP);
    int n = deg[i];
    n = n < CAP ? n : CAP;
    int n16 = (n + 15) & ~15;
    const unsigned int* hsc = hs2 + c2;
    unsigned int self = hsc[(long)i * 32];
    float selfL = bf_lo(self), selfH = bf_hi(self);
    float aL = selfL, aH = selfH;

    for (int e0 = 0; e0 < n16; e0 += 16) {
        int4 q0 = crow4[(e0 >> 2) + 0];
        int4 q1 = crow4[(e0 >> 2) + 1];
        int4 q2 = crow4[(e0 >> 2) + 2];
        int4 q3 = crow4[(e0 >> 2) + 3];
        unsigned int v[16];
        v[0]  = hsc[(long)q0.x * 32]; v[1]  = hsc[(long)q0.y * 32];
        v[2]  = hsc[(long)q0.z * 32]; v[3]  = hsc[(long)q0.w * 32];
        v[4]  = hsc[(long)q1.x * 32]; v[5]  = hsc[(long)q1.y * 32];
        v[6]  = hsc[(long)q1.z * 32]; v[7]  = hsc[(long)q1.w * 32];
        v[8]  = hsc[(long)q2.x * 32]; v[9]  = hsc[(long)q2.y * 32];
        v[10] = hsc[(long)q2.z * 32]; v[11] = hsc[(long)q2.w * 32];
        v[12] = hsc[(long)q3.x * 32]; v[13] = hsc[(long)q3.y * 32];
        v[14] = hsc[(long)q3.z * 32]; v[15] = hsc[(long)q3.w * 32];
#pragma unroll
        for (int j = 0; j < 16; ++j) {
            aL += bf_lo(v[j]);
            aH += bf_hi(v[j]);
        }
    }
    // remove surplus self contributions from the pad slots
    float fE = (float)(n16 - n);
    aL = fmaf(-fE, selfL, aL);
    aH = fmaf(-fE, selfH, aH);

    float di = dinv[i];
    float vL = fmaf(di, aL, bias[2 * c2]);
    float vH = fmaf(di, aH, bias[2 * c2 + 1]);
    float2 o;
    o.x = vL > 0.f ? vL : 0.f;
    o.y = vH > 0.f ? vH : 0.f;
    *reinterpret_cast<float2*>(&out[(long)i * 64 + 2 * c2]) = o;
}

// ---- graph boundaries from sorted batch ----
__global__ void k_bounds(const int* __restrict__ batch, int* __restrict__ start) {
    int i = blockIdx.x * blockDim.x + threadIdx.x;
    if (i >= N_NODES) return;
    int b = batch[i];
    int prev = (i == 0) ? -1 : batch[i - 1];
    for (int g = prev + 1; g <= b; ++g) start[g] = i;
    if (i == N_NODES - 1)
        for (int g = b + 1; g <= NG; ++g) start[g] = N_NODES;
}

// ---- fused mean-pool + head MLP: one 256-thread block per graph ----
__global__ void k_poolhead(const float* __restrict__ a, const int* __restrict__ start,
                           const float* __restrict__ Wc1, const float* __restrict__ bc1,
                           const float* __restrict__ Wc2, const float* __restrict__ bc2,
                           float* __restrict__ out) {
    __shared__ float partial[4][64];
    __shared__ float gvec[64];
    __shared__ float tvec[32];
    int g = blockIdx.x;
    int w = threadIdx.x >> 6;
    int j = threadIdx.x & 63;
    int s0 = start[g], s1 = start[g + 1];
    float acc = 0.f;
    for (int i = s0 + w; i < s1; i += 4)
        acc += a[(long)i * 64 + j];
    partial[w][j] = acc;
    __syncthreads();
    if (w == 0) {
        float c = (float)(s1 - s0);
        c = c > 1.f ? c : 1.f;
        gvec[j] = (partial[0][j] + partial[1][j] + partial[2][j] + partial[3][j]) / c;
    }
    __syncthreads();
    if (threadIdx.x < 32) {
        int jj = threadIdx.x;
        float acc2 = bc1[jj];
#pragma unroll 8
        for (int k = 0; k < 64; ++k) acc2 = fmaf(gvec[k], Wc1[k * 32 + jj], acc2);
        tvec[jj] = acc2 > 0.f ? acc2 : 0.f;
    }
    __syncthreads();
    if (threadIdx.x < 2) {
        int jj = threadIdx.x;
        float acc2 = bc2[jj];
#pragma unroll
        for (int k = 0; k < 32; ++k) acc2 = fmaf(tvec[k], Wc2[k * 2 + jj], acc2);
        out[g * 2 + jj] = acc2;
    }
}

extern "C" void kernel_launch(void* const* d_in, const int* in_sizes, int n_in,
                              void* d_out, int out_size, void* d_ws, size_t ws_size,
                              hipStream_t stream) {
    const float* x    = (const float*)d_in[0];
    const int*   ei   = (const int*)d_in[1];
    const int*   batch= (const int*)d_in[2];
    const float* W1   = (const float*)d_in[3];
    const float* b1   = (const float*)d_in[4];
    const float* W2   = (const float*)d_in[5];
    const float* b2   = (const float*)d_in[6];
    const float* Wc1  = (const float*)d_in[7];
    const float* bc1  = (const float*)d_in[8];
    const float* Wc2  = (const float*)d_in[9];
    const float* bc2  = (const float*)d_in[10];
    float* out = (float*)d_out;

    const int* src = ei;            // edge_index[0]
    const int* dst = ei + N_EDGES;  // edge_index[1]

    char* ws = (char*)d_ws;
    size_t off = 0;
    auto alloc = [&](size_t bytes) {
        void* p = ws + off;
        off += (bytes + 255) & ~(size_t)255;
        return p;
    };
    unsigned short* hs = (unsigned short*)alloc((size_t)N_NODES * HID * 2);   // 12.8MB bf16
    float* agg     = (float*)alloc((size_t)N_NODES * HID * sizeof(float));    // 25.6MB
    int*   col     = (int*)  alloc((size_t)N_NODES * CAP * sizeof(int) + 256);// 25.6MB padded CSR
    float* dinv    = (float*)alloc(N_NODES * sizeof(float));
    int*   fillpos = (int*)  alloc((N_NODES + 4) * sizeof(int));  // becomes deg
    int*   start   = (int*)  alloc((NG + 1) * sizeof(int));
    unsigned short* W1hi = (unsigned short*)alloc(64 * IN_CH * 2);  // transposed bf16
    unsigned short* W1lo = (unsigned short*)alloc(64 * IN_CH * 2);
    unsigned short* W2hi = (unsigned short*)alloc(64 * HID * 2);
    unsigned short* W2lo = (unsigned short*)alloc(64 * HID * 2);

    const int TB = 256;

    // weight transpose + hi/lo split (tiny)
    k_wcvt<<<(64 * IN_CH + TB - 1) / TB, TB, 0, stream>>>(W1, W1hi, W1lo, IN_CH);
    k_wcvt<<<(64 * HID + TB - 1) / TB, TB, 0, stream>>>(W2, W2hi, W2lo, HID);

    // padded CSR build: zero counts, fill passes, dinv + pad tails
    {
        const int nz4 = (N_NODES + 3) / 4;
        k_zero<<<(nz4 + TB - 1) / TB, TB, 0, stream>>>(fillpos, nz4);
        const int step = (N_NODES + NFILL - 1) / NFILL;
        for (int p = 0; p < NFILL; ++p) {
            int lo = p * step;
            int hi = lo + step < N_NODES ? lo + step : N_NODES;
            k_fill<<<(N_EDGES + TB - 1) / TB, TB, 0, stream>>>(src, dst, fillpos, col, lo, hi);
        }
        k_dinvpad<<<(N_NODES + TB - 1) / TB, TB, 0, stream>>>(fillpos, dinv, col);
    }

    // graph boundaries
    k_bounds<<<(N_NODES + TB - 1) / TB, TB, 0, stream>>>(batch, start);

    const int gatherBlocks = ((N_NODES + 1) / 2 * 64 + TB - 1) / TB;
    const int linBlocks = ((N_NODES + 15) / 16 + 3) / 4;   // 4 waves/block, 16 rows/wave

    // layer 1
    k_linear<IN_CH><<<linBlocks, 256, 0, stream>>>(x, W1hi, W1lo, dinv, hs);
    k_gather<<<gatherBlocks, TB, 0, stream>>>(fillpos, col, (const unsigned int*)hs, dinv, b1, agg);

    // layer 2
    k_linear<HID><<<linBlocks, 256, 0, stream>>>(agg, W2hi, W2lo, dinv, hs);
    k_gather<<<gatherBlocks, TB, 0, stream>>>(fillpos, col, (const unsigned int*)hs, dinv, b2, agg);

    // fused mean-pool + head
    k_poolhead<<<NG, 256, 0, stream>>>(agg, start, Wc1, bc1, Wc2, bc2, out);
}